// Round 5
// baseline (502.031 us; speedup 1.0000x reference)
//
#include <hip/hip_runtime.h>
#include <hip/hip_bf16.h>

// Quantizer: B=8, N=4096, D=64, K=8192
// probs = softmax(sim/T) over K;  z_q = probs @ codebook
// sim = l2norm(z) @ l2norm(emb)^T, sim in [-1,1] -> no online max needed.
// Round 5: passA was LDS-pipe-bound (~120 cyc/step: staged frags + etile).
// Fragment-interleaved global layout makes codebook frag loads contiguous
// (1KB/wave-instr) -> read frags DIRECTLY from global (L1-cached), drop all
// staging and barriers. LDS keeps only the per-wave etile. cvt_pk packing.

#define M_TOTAL 32768   // B*N
#define KCODES  8192
#define DDIM    64
#define KSPLIT  4
#define KCHUNK  (KCODES / KSPLIT)   // 2048

typedef __attribute__((ext_vector_type(8))) short bf16x8;
typedef __attribute__((ext_vector_type(4))) float f32x4;

__device__ inline unsigned short f2bf(float x) {
  union { float f; unsigned u; } v; v.f = x;
  unsigned r = v.u + 0x7FFFu + ((v.u >> 16) & 1u);  // RNE
  return (unsigned short)(r >> 16);
}

// One wave per row: L2-normalize, emit bf16 in MFMA-fragment-interleaved
// layout. Frag unit = 512 shorts (1KB). For A/B frags of 16x16x32:
//   F[(blk16*2+h)*512 + l*8 + j] = X[blk16*16 + (l&15)][h*32 + (l>>4)*8 + j]
// Transposed-frag copy (A operand of the U GEMM):
//   FT[(blk32*4+ds)*512 + l*8 + j] = X[blk32*32 + (l>>4)*8 + j][ds*16+(l&15)]
__global__ __launch_bounds__(256) void norm_rows_kernel(
    const float* __restrict__ in, unsigned short* __restrict__ F,
    unsigned short* __restrict__ FT, int nrows) {
  int row = blockIdx.x * 4 + (threadIdx.x >> 6);
  int d = threadIdx.x & 63;
  if (row >= nrows) return;
  float x = in[(size_t)row * DDIM + d];
  float s = x * x;
  s += __shfl_xor(s, 1);  s += __shfl_xor(s, 2);  s += __shfl_xor(s, 4);
  s += __shfl_xor(s, 8);  s += __shfl_xor(s, 16); s += __shfl_xor(s, 32);
  float scale = 1.0f / fmaxf(sqrtf(s), 1e-12f);
  unsigned short b = f2bf(x * scale);
  {
    int blk = row >> 4, ml = row & 15;
    int h = d >> 5, g = (d >> 3) & 3, j = d & 7;
    F[((size_t)(blk * 2 + h)) * 512 + (g * 16 + ml) * 8 + j] = b;
  }
  if (FT) {
    int ds = d >> 4, dl = d & 15;
    int kb = row >> 5, kg = (row >> 3) & 3, kj = row & 7;
    FT[((size_t)(kb * 4 + ds)) * 512 + (kg * 16 + dl) * 8 + kj] = b;
  }
}

// Pass A: 4 waves x 16 rows = 64 rows/block, K-chunk 2048, k-step 32.
// All codebook frags read directly from global (contiguous per wave, L1-hot).
// No __syncthreads anywhere; etile is per-wave.
__global__ __launch_bounds__(256) void passA_kernel(
    const unsigned short* __restrict__ FZn,
    const unsigned short* __restrict__ FCb,
    const unsigned short* __restrict__ FCbT,
    const float* __restrict__ tptr,
    float* __restrict__ Up,                  // [KSPLIT][32768][64] f32
    float* __restrict__ rsp) {               // [KSPLIT][32768]     f32
  __shared__ __align__(16) unsigned short etile[4][16 * 56];
  const int tid = threadIdx.x;
  const int w  = tid >> 6, l = tid & 63, g = l >> 4, ml = l & 15;
  const int rb = blockIdx.x & 511;
  const int ks = blockIdx.x >> 9;
  const int m_base = rb * 64 + w * 16;
  const int k0 = ks * KCHUNK;
  const float sc = 1.4426950408889634f / tptr[0];  // log2(e)/T

  const unsigned short* fz = FZn + ((size_t)((rb * 4 + w) * 2)) * 512;
  const bf16x8 zn0 = *(const bf16x8*)(fz + l * 8);
  const bf16x8 zn1 = *(const bf16x8*)(fz + 512 + l * 8);

  const f32x4 zero = {0.f, 0.f, 0.f, 0.f};
  f32x4 uacc[4] = {zero, zero, zero, zero};
  float rs = 0.f;

  for (int kc = k0; kc < k0 + KCHUNK; kc += 32) {
    const unsigned short* fc = FCb + (size_t)(kc >> 4) * 1024;   // 2x 16-code blks
    const unsigned short* ft = FCbT + (size_t)(kc >> 5) * 2048;  // 4 ds frags
#pragma unroll
    for (int cs = 0; cs < 2; ++cs) {
      const bf16x8 c0 = *(const bf16x8*)(fc + cs * 1024 + l * 8);
      const bf16x8 c1 = *(const bf16x8*)(fc + cs * 1024 + 512 + l * 8);
      f32x4 acc = __builtin_amdgcn_mfma_f32_16x16x32_bf16(c0, zn0, zero, 0, 0, 0);
      acc = __builtin_amdgcn_mfma_f32_16x16x32_bf16(c1, zn1, acc, 0, 0, 0);
      float e0 = exp2f((acc[0] - 1.0f) * sc);  // exp((sim-1)/T) <= 1
      float e1 = exp2f((acc[1] - 1.0f) * sc);
      float e2 = exp2f((acc[2] - 1.0f) * sc);
      float e3 = exp2f((acc[3] - 1.0f) * sc);
      rs += (e0 + e1) + (e2 + e3);
      union { __hip_bfloat162 h[2]; uint2 u; } pk;
      pk.h[0] = __float22bfloat162_rn(make_float2(e0, e1));  // v_cvt_pk_bf16_f32
      pk.h[1] = __float22bfloat162_rn(make_float2(e2, e3));
      *(uint2*)&etile[w][ml * 56 + cs * 16 + g * 4] = pk.u;
    }
    asm volatile("s_waitcnt lgkmcnt(0)" ::: "memory");  // same-wave LDS dep
    const bf16x8 ef = *(const bf16x8*)&etile[w][ml * 56 + g * 8];
#pragma unroll
    for (int ds = 0; ds < 4; ++ds) {
      const bf16x8 ct = *(const bf16x8*)(ft + ds * 512 + l * 8);
      uacc[ds] = __builtin_amdgcn_mfma_f32_16x16x32_bf16(ct, ef, uacc[ds], 0, 0, 0);
    }
  }

  rs += __shfl_xor(rs, 16);
  rs += __shfl_xor(rs, 32);
  if (g == 0) rsp[(size_t)ks * M_TOTAL + m_base + ml] = rs;

  float* urow = Up + ((size_t)ks * M_TOTAL + m_base + ml) * DDIM;
#pragma unroll
  for (int ds = 0; ds < 4; ++ds)
    *(f32x4*)(urow + ds * 16 + g * 4) = uacc[ds];
}

// rs[m] = sum of partials; z_q = (sum of U partials) / rs. One f32x4/thread.
__global__ __launch_bounds__(256) void rszq_kernel(
    const float* __restrict__ Up, const float* __restrict__ rsp,
    float* __restrict__ rs, float* __restrict__ zq) {
  size_t i = (size_t)blockIdx.x * 256 + threadIdx.x;
  int m = (int)(i >> 4);
  float s = rsp[m] + rsp[M_TOTAL + m] + rsp[2 * M_TOTAL + m] + rsp[3 * M_TOTAL + m];
  if ((i & 15) == 0) rs[m] = s;
  f32x4 u = *(const f32x4*)(Up + i * 4);
#pragma unroll
  for (int ks = 1; ks < KSPLIT; ++ks) {
    f32x4 p = *(const f32x4*)(Up + (size_t)ks * M_TOTAL * DDIM + i * 4);
#pragma unroll
    for (int r = 0; r < 4; ++r) u[r] += p[r];
  }
  float inv = 1.0f / s;
  f32x4 v = {u[0] * inv, u[1] * inv, u[2] * inv, u[3] * inv};
  *(f32x4*)(zq + i * 4) = v;
}

// Pass B: 4 waves x 16 rows, direct global frag reads, no LDS, no barriers.
__global__ __launch_bounds__(256) void probs_kernel(
    const unsigned short* __restrict__ FZn,
    const unsigned short* __restrict__ FCb,
    const float* __restrict__ tptr,
    const float* __restrict__ rsv,
    float* __restrict__ probs) {
  const int tid = threadIdx.x;
  const int w  = tid >> 6, l = tid & 63, g = l >> 4, ml = l & 15;
  const int rb = blockIdx.x & 511;
  const int ks = blockIdx.x >> 9;
  const int m_base = rb * 64 + w * 16;
  const int k0 = ks * KCHUNK;
  const float sc = 1.4426950408889634f / tptr[0];

  const unsigned short* fz = FZn + ((size_t)((rb * 4 + w) * 2)) * 512;
  const bf16x8 zn0 = *(const bf16x8*)(fz + l * 8);
  const bf16x8 zn1 = *(const bf16x8*)(fz + 512 + l * 8);
  const float inv = 1.0f / rsv[m_base + ml];
  const f32x4 zero = {0.f, 0.f, 0.f, 0.f};
  float* prow = probs + (size_t)(m_base + ml) * KCODES;

  for (int kc = k0; kc < k0 + KCHUNK; kc += 32) {
    const unsigned short* fc = FCb + (size_t)(kc >> 4) * 1024;
#pragma unroll
    for (int cs = 0; cs < 2; ++cs) {
      const bf16x8 c0 = *(const bf16x8*)(fc + cs * 1024 + l * 8);
      const bf16x8 c1 = *(const bf16x8*)(fc + cs * 1024 + 512 + l * 8);
      f32x4 a = __builtin_amdgcn_mfma_f32_16x16x32_bf16(c0, zn0, zero, 0, 0, 0);
      a = __builtin_amdgcn_mfma_f32_16x16x32_bf16(c1, zn1, a, 0, 0, 0);
      f32x4 p;
#pragma unroll
      for (int r = 0; r < 4; ++r) p[r] = exp2f((a[r] - 1.0f) * sc) * inv;
      *(f32x4*)(prow + kc + cs * 16 + g * 4) = p;
    }
  }
}

extern "C" void kernel_launch(void* const* d_in, const int* in_sizes, int n_in,
                              void* d_out, int out_size, void* d_ws, size_t ws_size,
                              hipStream_t stream) {
  const float* z    = (const float*)d_in[0];
  const float* emb  = (const float*)d_in[1];
  const float* temp = (const float*)d_in[2];

  float* probs = (float*)d_out;
  float* zq    = probs + (size_t)M_TOTAL * KCODES;

  unsigned short* FZn  = (unsigned short*)d_ws;             // 4 MB
  unsigned short* FCb  = FZn + (size_t)M_TOTAL * DDIM;      // 1 MB
  unsigned short* FCbT = FCb + (size_t)KCODES * DDIM;       // 1 MB
  float* Up  = (float*)(FCbT + (size_t)KCODES * DDIM);      // 32 MB
  float* rsp = Up + (size_t)KSPLIT * M_TOTAL * DDIM;        // 512 KB
  float* rs  = rsp + (size_t)KSPLIT * M_TOTAL;              // 128 KB

  norm_rows_kernel<<<M_TOTAL / 4, 256, 0, stream>>>(z, FZn, nullptr, M_TOTAL);
  norm_rows_kernel<<<KCODES / 4, 256, 0, stream>>>(emb, FCb, FCbT, KCODES);
  passA_kernel<<<512 * KSPLIT, 256, 0, stream>>>(FZn, FCb, FCbT, temp, Up, rsp);
  rszq_kernel<<<(M_TOTAL * DDIM / 4) / 256, 256, 0, stream>>>(Up, rsp, rs, zq);
  probs_kernel<<<512 * KSPLIT, 256, 0, stream>>>(FZn, FCb, temp, rs, probs);
}

// Round 6
// 378.641 us; speedup vs baseline: 1.3259x; 1.3259x over previous
//
#include <hip/hip_runtime.h>
#include <hip/hip_bf16.h>

// Quantizer: B=8, N=4096, D=64, K=8192
// probs = softmax(sim/T) over K;  z_q = probs @ codebook
// sim = l2norm(z) @ l2norm(emb)^T, sim in [-1,1] -> no online max needed.
// Round 6: R5 (no staging) regressed -> L1 can't hold the 256KB chunk, every
// wave paid its own L2 traffic + latency. Revert to R4 staged structure and
// attack its LDS-pipe bound instead: each wave computes TWO 16-row tiles per
// staged k-step, so the 8 codebook-frag b128 reads (96 cyc) amortize 2x.

#define M_TOTAL 32768   // B*N
#define KCODES  8192
#define DDIM    64
#define KSPLIT  4
#define KCHUNK  (KCODES / KSPLIT)   // 2048

typedef __attribute__((ext_vector_type(8))) short bf16x8;
typedef __attribute__((ext_vector_type(4))) float f32x4;

__device__ inline unsigned short f2bf(float x) {
  union { float f; unsigned u; } v; v.f = x;
  unsigned r = v.u + 0x7FFFu + ((v.u >> 16) & 1u);  // RNE
  return (unsigned short)(r >> 16);
}

// One wave per row: L2-normalize, emit bf16 in MFMA-fragment-interleaved
// layout. Frag unit = 512 shorts (1KB). For A/B frags of 16x16x32:
//   F[(blk16*2+h)*512 + (g*16+ml)*8 + j] = X[blk16*16 + ml][h*32 + g*8 + j]
// Transposed-frag copy (A operand of the U GEMM):
//   FT[(blk32*4+ds)*512 + (kg*16+dl)*8 + kj] = X[blk32*32 + kg*8+kj][ds*16+dl]
__global__ __launch_bounds__(256) void norm_rows_kernel(
    const float* __restrict__ in, unsigned short* __restrict__ F,
    unsigned short* __restrict__ FT, int nrows) {
  int row = blockIdx.x * 4 + (threadIdx.x >> 6);
  int d = threadIdx.x & 63;
  if (row >= nrows) return;
  float x = in[(size_t)row * DDIM + d];
  float s = x * x;
  s += __shfl_xor(s, 1);  s += __shfl_xor(s, 2);  s += __shfl_xor(s, 4);
  s += __shfl_xor(s, 8);  s += __shfl_xor(s, 16); s += __shfl_xor(s, 32);
  float scale = 1.0f / fmaxf(sqrtf(s), 1e-12f);
  unsigned short b = f2bf(x * scale);
  {
    int blk = row >> 4, ml = row & 15;
    int h = d >> 5, g = (d >> 3) & 3, j = d & 7;
    F[((size_t)(blk * 2 + h)) * 512 + (g * 16 + ml) * 8 + j] = b;
  }
  if (FT) {
    int ds = d >> 4, dl = d & 15;
    int kb = row >> 5, kg = (row >> 3) & 3, kj = row & 7;
    FT[((size_t)(kb * 4 + ds)) * 512 + (kg * 16 + dl) * 8 + kj] = b;
  }
}

// Pass A: 8 waves x 2 tiles x 16 rows = 256 rows/block, k-step 32, dbuf LDS.
// Codebook frags read from LDS ONCE per step, reused by both row-tiles.
__global__ __launch_bounds__(512, 4) void passA_kernel(
    const unsigned short* __restrict__ FZn,
    const unsigned short* __restrict__ FCb,
    const unsigned short* __restrict__ FCbT,
    const float* __restrict__ tptr,
    float* __restrict__ Up,                  // [KSPLIT][32768][64] f32
    float* __restrict__ rsp) {               // [KSPLIT][32768]     f32
  __shared__ __align__(16) unsigned short sbuf[2][4096];      // 2 x 8KB
  __shared__ __align__(16) unsigned short etile[8][2][16 * 56];
  const int tid = threadIdx.x;
  const int w  = tid >> 6, l = tid & 63, g = l >> 4, ml = l & 15;
  const int rb = blockIdx.x & 127;
  const int ks = blockIdx.x >> 7;
  const int mA = rb * 256 + w * 32;        // tile A rows
  const int mB = mA + 16;                  // tile B rows
  const int k0 = ks * KCHUNK;
  const float sc = 1.4426950408889634f / tptr[0];  // log2(e)/T

  // z fragments for both tiles (frag blk16 = rb*16 + w*2 {+1})
  const unsigned short* fz = FZn + ((size_t)((rb * 16 + w * 2) * 2)) * 512;
  const bf16x8 zA0 = *(const bf16x8*)(fz + l * 8);
  const bf16x8 zA1 = *(const bf16x8*)(fz + 512 + l * 8);
  const bf16x8 zB0 = *(const bf16x8*)(fz + 1024 + l * 8);
  const bf16x8 zB1 = *(const bf16x8*)(fz + 1536 + l * 8);

  const f32x4 zero = {0.f, 0.f, 0.f, 0.f};
  f32x4 uaccA[4] = {zero, zero, zero, zero};
  f32x4 uaccB[4] = {zero, zero, zero, zero};
  float rsA = 0.f, rsB = 0.f;

  // staging: t<256 -> FCb 32 codes (4KB); t>=256 -> FCbT 32 codes (4KB)
  const unsigned short* gb = (tid < 256 ? FCb : FCbT) + (size_t)(tid & 255) * 8;
  bf16x8 stg = *(const bf16x8*)(gb + (size_t)k0 * 64);
  int cur = 0;

  const int NIT = KCHUNK / 32;  // 64
  for (int it = 0; it < NIT; ++it) {
    *(bf16x8*)&sbuf[cur][tid * 8] = stg;
    if (it + 1 < NIT)
      stg = *(const bf16x8*)(gb + (size_t)(k0 + (it + 1) * 32) * 64);
    __syncthreads();
    const unsigned short* sb = &sbuf[cur][0];
#pragma unroll
    for (int cs = 0; cs < 2; ++cs) {
      const bf16x8 c0 = *(const bf16x8*)(sb + cs * 1024 + l * 8);
      const bf16x8 c1 = *(const bf16x8*)(sb + cs * 1024 + 512 + l * 8);
      f32x4 aA = __builtin_amdgcn_mfma_f32_16x16x32_bf16(c0, zA0, zero, 0, 0, 0);
      aA = __builtin_amdgcn_mfma_f32_16x16x32_bf16(c1, zA1, aA, 0, 0, 0);
      f32x4 aB = __builtin_amdgcn_mfma_f32_16x16x32_bf16(c0, zB0, zero, 0, 0, 0);
      aB = __builtin_amdgcn_mfma_f32_16x16x32_bf16(c1, zB1, aB, 0, 0, 0);
      float eA0 = exp2f((aA[0] - 1.0f) * sc), eA1 = exp2f((aA[1] - 1.0f) * sc);
      float eA2 = exp2f((aA[2] - 1.0f) * sc), eA3 = exp2f((aA[3] - 1.0f) * sc);
      float eB0 = exp2f((aB[0] - 1.0f) * sc), eB1 = exp2f((aB[1] - 1.0f) * sc);
      float eB2 = exp2f((aB[2] - 1.0f) * sc), eB3 = exp2f((aB[3] - 1.0f) * sc);
      rsA += (eA0 + eA1) + (eA2 + eA3);
      rsB += (eB0 + eB1) + (eB2 + eB3);
      union { __hip_bfloat162 h[2]; uint2 u; } pA, pB;
      pA.h[0] = __float22bfloat162_rn(make_float2(eA0, eA1));
      pA.h[1] = __float22bfloat162_rn(make_float2(eA2, eA3));
      pB.h[0] = __float22bfloat162_rn(make_float2(eB0, eB1));
      pB.h[1] = __float22bfloat162_rn(make_float2(eB2, eB3));
      *(uint2*)&etile[w][0][ml * 56 + cs * 16 + g * 4] = pA.u;
      *(uint2*)&etile[w][1][ml * 56 + cs * 16 + g * 4] = pB.u;
    }
    asm volatile("s_waitcnt lgkmcnt(0)" ::: "memory");  // same-wave LDS dep
    const bf16x8 efA = *(const bf16x8*)&etile[w][0][ml * 56 + g * 8];
    const bf16x8 efB = *(const bf16x8*)&etile[w][1][ml * 56 + g * 8];
#pragma unroll
    for (int ds = 0; ds < 4; ++ds) {
      const bf16x8 ct = *(const bf16x8*)(sb + 2048 + ds * 512 + l * 8);
      uaccA[ds] = __builtin_amdgcn_mfma_f32_16x16x32_bf16(ct, efA, uaccA[ds], 0, 0, 0);
      uaccB[ds] = __builtin_amdgcn_mfma_f32_16x16x32_bf16(ct, efB, uaccB[ds], 0, 0, 0);
    }
    cur ^= 1;
  }

  rsA += __shfl_xor(rsA, 16);  rsA += __shfl_xor(rsA, 32);
  rsB += __shfl_xor(rsB, 16);  rsB += __shfl_xor(rsB, 32);
  if (g == 0) {
    rsp[(size_t)ks * M_TOTAL + mA + ml] = rsA;
    rsp[(size_t)ks * M_TOTAL + mB + ml] = rsB;
  }

  float* urA = Up + ((size_t)ks * M_TOTAL + mA + ml) * DDIM;
  float* urB = Up + ((size_t)ks * M_TOTAL + mB + ml) * DDIM;
#pragma unroll
  for (int ds = 0; ds < 4; ++ds) {
    *(f32x4*)(urA + ds * 16 + g * 4) = uaccA[ds];
    *(f32x4*)(urB + ds * 16 + g * 4) = uaccB[ds];
  }
}

// rs[m] = sum of partials; z_q = (sum of U partials) / rs. One f32x4/thread.
__global__ __launch_bounds__(256) void rszq_kernel(
    const float* __restrict__ Up, const float* __restrict__ rsp,
    float* __restrict__ rs, float* __restrict__ zq) {
  size_t i = (size_t)blockIdx.x * 256 + threadIdx.x;
  int m = (int)(i >> 4);
  float s = rsp[m] + rsp[M_TOTAL + m] + rsp[2 * M_TOTAL + m] + rsp[3 * M_TOTAL + m];
  if ((i & 15) == 0) rs[m] = s;
  f32x4 u = *(const f32x4*)(Up + i * 4);
#pragma unroll
  for (int ks = 1; ks < KSPLIT; ++ks) {
    f32x4 p = *(const f32x4*)(Up + (size_t)ks * M_TOTAL * DDIM + i * 4);
#pragma unroll
    for (int r = 0; r < 4; ++r) u[r] += p[r];
  }
  float inv = 1.0f / s;
  f32x4 v = {u[0] * inv, u[1] * inv, u[2] * inv, u[3] * inv};
  *(f32x4*)(zq + i * 4) = v;
}

// Pass B: 8 waves x 16 rows = 128 rows/block, k-step 64 (8KB staged, dbuf).
__global__ __launch_bounds__(512, 4) void probs_kernel(
    const unsigned short* __restrict__ FZn,
    const unsigned short* __restrict__ FCb,
    const float* __restrict__ tptr,
    const float* __restrict__ rsv,
    float* __restrict__ probs) {
  __shared__ __align__(16) unsigned short sbuf[2][4096];
  const int tid = threadIdx.x;
  const int w  = tid >> 6, l = tid & 63, g = l >> 4, ml = l & 15;
  const int rb = blockIdx.x & 255;
  const int ks = blockIdx.x >> 8;
  const int m_base = rb * 128 + w * 16;
  const int k0 = ks * KCHUNK;
  const float sc = 1.4426950408889634f / tptr[0];

  const unsigned short* fz = FZn + ((size_t)((rb * 8 + w) * 2)) * 512;
  const bf16x8 zn0 = *(const bf16x8*)(fz + l * 8);
  const bf16x8 zn1 = *(const bf16x8*)(fz + 512 + l * 8);
  const float inv = 1.0f / rsv[m_base + ml];
  const f32x4 zero = {0.f, 0.f, 0.f, 0.f};
  float* prow = probs + (size_t)(m_base + ml) * KCODES;

  const unsigned short* gb = FCb + (size_t)tid * 8;  // 512 thr x 16B = 8KB/step
  bf16x8 stg = *(const bf16x8*)(gb + (size_t)k0 * 64);
  int cur = 0;

  const int NIT = KCHUNK / 64;  // 32
  for (int it = 0; it < NIT; ++it) {
    *(bf16x8*)&sbuf[cur][tid * 8] = stg;
    if (it + 1 < NIT)
      stg = *(const bf16x8*)(gb + (size_t)(k0 + (it + 1) * 64) * 64);
    __syncthreads();
    const unsigned short* sb = &sbuf[cur][0];
    const int kc = k0 + it * 64;
#pragma unroll
    for (int cb = 0; cb < 4; ++cb) {
      const bf16x8 c0 = *(const bf16x8*)(sb + (cb * 2 + 0) * 512 + l * 8);
      const bf16x8 c1 = *(const bf16x8*)(sb + (cb * 2 + 1) * 512 + l * 8);
      f32x4 a = __builtin_amdgcn_mfma_f32_16x16x32_bf16(c0, zn0, zero, 0, 0, 0);
      a = __builtin_amdgcn_mfma_f32_16x16x32_bf16(c1, zn1, a, 0, 0, 0);
      f32x4 p;
#pragma unroll
      for (int r = 0; r < 4; ++r) p[r] = exp2f((a[r] - 1.0f) * sc) * inv;
      *(f32x4*)(prow + kc + cb * 16 + g * 4) = p;
    }
    cur ^= 1;
  }
}

extern "C" void kernel_launch(void* const* d_in, const int* in_sizes, int n_in,
                              void* d_out, int out_size, void* d_ws, size_t ws_size,
                              hipStream_t stream) {
  const float* z    = (const float*)d_in[0];
  const float* emb  = (const float*)d_in[1];
  const float* temp = (const float*)d_in[2];

  float* probs = (float*)d_out;
  float* zq    = probs + (size_t)M_TOTAL * KCODES;

  unsigned short* FZn  = (unsigned short*)d_ws;             // 4 MB
  unsigned short* FCb  = FZn + (size_t)M_TOTAL * DDIM;      // 1 MB
  unsigned short* FCbT = FCb + (size_t)KCODES * DDIM;       // 1 MB
  float* Up  = (float*)(FCbT + (size_t)KCODES * DDIM);      // 32 MB
  float* rsp = Up + (size_t)KSPLIT * M_TOTAL * DDIM;        // 512 KB
  float* rs  = rsp + (size_t)KSPLIT * M_TOTAL;              // 128 KB

  norm_rows_kernel<<<M_TOTAL / 4, 256, 0, stream>>>(z, FZn, nullptr, M_TOTAL);
  norm_rows_kernel<<<KCODES / 4, 256, 0, stream>>>(emb, FCb, FCbT, KCODES);
  passA_kernel<<<128 * KSPLIT, 512, 0, stream>>>(FZn, FCb, FCbT, temp, Up, rsp);
  rszq_kernel<<<(M_TOTAL * DDIM / 4) / 256, 256, 0, stream>>>(Up, rsp, rs, zq);
  probs_kernel<<<256 * KSPLIT, 512, 0, stream>>>(FZn, FCb, temp, rs, probs);
}

// Round 7
// 368.493 us; speedup vs baseline: 1.3624x; 1.0275x over previous
//
#include <hip/hip_runtime.h>
#include <hip/hip_bf16.h>

// Quantizer: B=8, N=4096, D=64, K=8192
// probs = softmax(sim/T) over K;  z_q = probs @ codebook
// sim = l2norm(z) @ l2norm(emb)^T, sim in [-1,1] -> no online max needed.
// Round 7: re-partition. pass1 = rowsum ONLY (2-tile, cheap). pass2 = probs
// store + U-GEMM: the etile/FCbT/U machinery moves under the HBM-write-bound
// pass where LDS/VALU pipes are idle. zq = plain sum of Up partials (etile
// packs normalized p, so no final division).

#define M_TOTAL 32768   // B*N
#define KCODES  8192
#define DDIM    64
#define KSPLIT  4
#define KCHUNK  (KCODES / KSPLIT)   // 2048

typedef __attribute__((ext_vector_type(8))) short bf16x8;
typedef __attribute__((ext_vector_type(4))) float f32x4;

__device__ inline unsigned short f2bf(float x) {
  union { float f; unsigned u; } v; v.f = x;
  unsigned r = v.u + 0x7FFFu + ((v.u >> 16) & 1u);  // RNE
  return (unsigned short)(r >> 16);
}

// One wave per row: L2-normalize, emit bf16 in MFMA-fragment-interleaved
// layout. Frag unit = 512 shorts (1KB). For A/B frags of 16x16x32:
//   F[(blk16*2+h)*512 + (g*16+ml)*8 + j] = X[blk16*16 + ml][h*32 + g*8 + j]
// Transposed-frag copy (A operand of the U GEMM):
//   FT[(blk32*4+ds)*512 + (kg*16+dl)*8 + kj] = X[blk32*32 + kg*8+kj][ds*16+dl]
__global__ __launch_bounds__(256) void norm_rows_kernel(
    const float* __restrict__ in, unsigned short* __restrict__ F,
    unsigned short* __restrict__ FT, int nrows) {
  int row = blockIdx.x * 4 + (threadIdx.x >> 6);
  int d = threadIdx.x & 63;
  if (row >= nrows) return;
  float x = in[(size_t)row * DDIM + d];
  float s = x * x;
  s += __shfl_xor(s, 1);  s += __shfl_xor(s, 2);  s += __shfl_xor(s, 4);
  s += __shfl_xor(s, 8);  s += __shfl_xor(s, 16); s += __shfl_xor(s, 32);
  float scale = 1.0f / fmaxf(sqrtf(s), 1e-12f);
  unsigned short b = f2bf(x * scale);
  {
    int blk = row >> 4, ml = row & 15;
    int h = d >> 5, g = (d >> 3) & 3, j = d & 7;
    F[((size_t)(blk * 2 + h)) * 512 + (g * 16 + ml) * 8 + j] = b;
  }
  if (FT) {
    int ds = d >> 4, dl = d & 15;
    int kb = row >> 5, kg = (row >> 3) & 3, kj = row & 7;
    FT[((size_t)(kb * 4 + ds)) * 512 + (kg * 16 + dl) * 8 + kj] = b;
  }
}

// pass1: rowsum of exp only. 8 waves x 2 tiles x 16 rows = 256 rows/block,
// k-step 64 (8KB FCb staged by 512 threads, dbuf). No etile, no FCbT, no U.
__global__ __launch_bounds__(512, 4) void pass1_kernel(
    const unsigned short* __restrict__ FZn,
    const unsigned short* __restrict__ FCb,
    const float* __restrict__ tptr,
    float* __restrict__ rsp) {               // [KSPLIT][32768] f32
  __shared__ __align__(16) unsigned short sbuf[2][4096];   // 2 x 8KB
  const int tid = threadIdx.x;
  const int w  = tid >> 6, l = tid & 63, g = l >> 4, ml = l & 15;
  const int rb = blockIdx.x & 127;
  const int ks = blockIdx.x >> 7;
  const int mA = rb * 256 + w * 32;
  const int mB = mA + 16;
  const int k0 = ks * KCHUNK;
  const float sc = 1.4426950408889634f / tptr[0];  // log2(e)/T

  const unsigned short* fz = FZn + ((size_t)((rb * 16 + w * 2) * 2)) * 512;
  const bf16x8 zA0 = *(const bf16x8*)(fz + l * 8);
  const bf16x8 zA1 = *(const bf16x8*)(fz + 512 + l * 8);
  const bf16x8 zB0 = *(const bf16x8*)(fz + 1024 + l * 8);
  const bf16x8 zB1 = *(const bf16x8*)(fz + 1536 + l * 8);

  const f32x4 zero = {0.f, 0.f, 0.f, 0.f};
  float rsA = 0.f, rsB = 0.f;

  const unsigned short* gb = FCb + (size_t)tid * 8;   // 512 thr x 16B = 64 codes
  bf16x8 stg = *(const bf16x8*)(gb + (size_t)k0 * 64);
  int cur = 0;

  const int NIT = KCHUNK / 64;  // 32
  for (int it = 0; it < NIT; ++it) {
    *(bf16x8*)&sbuf[cur][tid * 8] = stg;
    if (it + 1 < NIT)
      stg = *(const bf16x8*)(gb + (size_t)(k0 + (it + 1) * 64) * 64);
    __syncthreads();
    const unsigned short* sb = &sbuf[cur][0];
#pragma unroll
    for (int cb = 0; cb < 4; ++cb) {
      const bf16x8 c0 = *(const bf16x8*)(sb + cb * 1024 + l * 8);
      const bf16x8 c1 = *(const bf16x8*)(sb + cb * 1024 + 512 + l * 8);
      f32x4 aA = __builtin_amdgcn_mfma_f32_16x16x32_bf16(c0, zA0, zero, 0, 0, 0);
      aA = __builtin_amdgcn_mfma_f32_16x16x32_bf16(c1, zA1, aA, 0, 0, 0);
      f32x4 aB = __builtin_amdgcn_mfma_f32_16x16x32_bf16(c0, zB0, zero, 0, 0, 0);
      aB = __builtin_amdgcn_mfma_f32_16x16x32_bf16(c1, zB1, aB, 0, 0, 0);
      rsA += (exp2f((aA[0] - 1.0f) * sc) + exp2f((aA[1] - 1.0f) * sc))
           + (exp2f((aA[2] - 1.0f) * sc) + exp2f((aA[3] - 1.0f) * sc));
      rsB += (exp2f((aB[0] - 1.0f) * sc) + exp2f((aB[1] - 1.0f) * sc))
           + (exp2f((aB[2] - 1.0f) * sc) + exp2f((aB[3] - 1.0f) * sc));
    }
    cur ^= 1;
  }

  rsA += __shfl_xor(rsA, 16);  rsA += __shfl_xor(rsA, 32);
  rsB += __shfl_xor(rsB, 16);  rsB += __shfl_xor(rsB, 32);
  if (g == 0) {
    rsp[(size_t)ks * M_TOTAL + mA + ml] = rsA;
    rsp[(size_t)ks * M_TOTAL + mB + ml] = rsB;
  }
}

// rs[m] = sum of KSPLIT partials
__global__ __launch_bounds__(256) void rs_kernel(
    const float* __restrict__ rsp, float* __restrict__ rs) {
  int m = blockIdx.x * 256 + threadIdx.x;
  float s = 0.f;
#pragma unroll
  for (int ks = 0; ks < KSPLIT; ++ks) s += rsp[(size_t)ks * M_TOTAL + m];
  rs[m] = s;
}

// pass2: probs write + U accumulation. 8 waves x 16 rows = 128 rows/block,
// k-step 32 (FCb 4KB + FCbT 4KB staged, dbuf). etile packs NORMALIZED p, so
// Up partials sum directly to z_q.
__global__ __launch_bounds__(512, 2) void pass2_kernel(
    const unsigned short* __restrict__ FZn,
    const unsigned short* __restrict__ FCb,
    const unsigned short* __restrict__ FCbT,
    const float* __restrict__ tptr,
    const float* __restrict__ rsv,
    float* __restrict__ probs,
    float* __restrict__ Up) {                // [KSPLIT][32768][64] f32
  __shared__ __align__(16) unsigned short sbuf[2][4096];      // 2 x 8KB
  __shared__ __align__(16) unsigned short etile[8][16 * 56];
  const int tid = threadIdx.x;
  const int w  = tid >> 6, l = tid & 63, g = l >> 4, ml = l & 15;
  const int rb = blockIdx.x & 255;
  const int ks = blockIdx.x >> 8;
  const int m_base = rb * 128 + w * 16;
  const int k0 = ks * KCHUNK;
  const float sc = 1.4426950408889634f / tptr[0];

  const unsigned short* fz = FZn + ((size_t)((rb * 8 + w) * 2)) * 512;
  const bf16x8 zn0 = *(const bf16x8*)(fz + l * 8);
  const bf16x8 zn1 = *(const bf16x8*)(fz + 512 + l * 8);
  const float inv = 1.0f / rsv[m_base + ml];
  const f32x4 zero = {0.f, 0.f, 0.f, 0.f};
  f32x4 uacc[4] = {zero, zero, zero, zero};
  float* prow = probs + (size_t)(m_base + ml) * KCODES;

  // staging: t<256 -> FCb 32 codes (4KB); t>=256 -> FCbT 32 codes (4KB)
  const unsigned short* gb = (tid < 256 ? FCb : FCbT) + (size_t)(tid & 255) * 8;
  bf16x8 stg = *(const bf16x8*)(gb + (size_t)k0 * 64);
  int cur = 0;

  const int NIT = KCHUNK / 32;  // 64
  for (int it = 0; it < NIT; ++it) {
    *(bf16x8*)&sbuf[cur][tid * 8] = stg;
    if (it + 1 < NIT)
      stg = *(const bf16x8*)(gb + (size_t)(k0 + (it + 1) * 32) * 64);
    __syncthreads();
    const unsigned short* sb = &sbuf[cur][0];
    const int kc = k0 + it * 32;
#pragma unroll
    for (int cs = 0; cs < 2; ++cs) {
      const bf16x8 c0 = *(const bf16x8*)(sb + cs * 1024 + l * 8);
      const bf16x8 c1 = *(const bf16x8*)(sb + cs * 1024 + 512 + l * 8);
      f32x4 a = __builtin_amdgcn_mfma_f32_16x16x32_bf16(c0, zn0, zero, 0, 0, 0);
      a = __builtin_amdgcn_mfma_f32_16x16x32_bf16(c1, zn1, a, 0, 0, 0);
      f32x4 p;
      p[0] = exp2f((a[0] - 1.0f) * sc) * inv;
      p[1] = exp2f((a[1] - 1.0f) * sc) * inv;
      p[2] = exp2f((a[2] - 1.0f) * sc) * inv;
      p[3] = exp2f((a[3] - 1.0f) * sc) * inv;
      *(f32x4*)(prow + kc + cs * 16 + g * 4) = p;   // coalesced probs store
      union { __hip_bfloat162 h[2]; uint2 u; } pk;
      pk.h[0] = __float22bfloat162_rn(make_float2(p[0], p[1]));
      pk.h[1] = __float22bfloat162_rn(make_float2(p[2], p[3]));
      *(uint2*)&etile[w][ml * 56 + cs * 16 + g * 4] = pk.u;
    }
    asm volatile("s_waitcnt lgkmcnt(0)" ::: "memory");  // same-wave LDS dep
    const bf16x8 ef = *(const bf16x8*)&etile[w][ml * 56 + g * 8];
#pragma unroll
    for (int ds = 0; ds < 4; ++ds) {
      const bf16x8 ct = *(const bf16x8*)(sb + 2048 + ds * 512 + l * 8);
      uacc[ds] = __builtin_amdgcn_mfma_f32_16x16x32_bf16(ct, ef, uacc[ds], 0, 0, 0);
    }
    cur ^= 1;
  }

  float* urow = Up + ((size_t)ks * M_TOTAL + m_base + ml) * DDIM;
#pragma unroll
  for (int ds = 0; ds < 4; ++ds)
    *(f32x4*)(urow + ds * 16 + g * 4) = uacc[ds];
}

// z_q = sum of Up partials (p already normalized in etile)
__global__ __launch_bounds__(256) void zq_kernel(
    const float* __restrict__ Up, float* __restrict__ zq) {
  size_t i = (size_t)blockIdx.x * 256 + threadIdx.x;  // one f32x4 per thread
  f32x4 u = *(const f32x4*)(Up + i * 4);
#pragma unroll
  for (int ks = 1; ks < KSPLIT; ++ks) {
    f32x4 p = *(const f32x4*)(Up + (size_t)ks * M_TOTAL * DDIM + i * 4);
#pragma unroll
    for (int r = 0; r < 4; ++r) u[r] += p[r];
  }
  *(f32x4*)(zq + i * 4) = u;
}

extern "C" void kernel_launch(void* const* d_in, const int* in_sizes, int n_in,
                              void* d_out, int out_size, void* d_ws, size_t ws_size,
                              hipStream_t stream) {
  const float* z    = (const float*)d_in[0];
  const float* emb  = (const float*)d_in[1];
  const float* temp = (const float*)d_in[2];

  float* probs = (float*)d_out;
  float* zq    = probs + (size_t)M_TOTAL * KCODES;

  unsigned short* FZn  = (unsigned short*)d_ws;             // 4 MB
  unsigned short* FCb  = FZn + (size_t)M_TOTAL * DDIM;      // 1 MB
  unsigned short* FCbT = FCb + (size_t)KCODES * DDIM;       // 1 MB
  float* Up  = (float*)(FCbT + (size_t)KCODES * DDIM);      // 32 MB
  float* rsp = Up + (size_t)KSPLIT * M_TOTAL * DDIM;        // 512 KB
  float* rs  = rsp + (size_t)KSPLIT * M_TOTAL;              // 128 KB

  norm_rows_kernel<<<M_TOTAL / 4, 256, 0, stream>>>(z, FZn, nullptr, M_TOTAL);
  norm_rows_kernel<<<KCODES / 4, 256, 0, stream>>>(emb, FCb, FCbT, KCODES);
  pass1_kernel<<<128 * KSPLIT, 512, 0, stream>>>(FZn, FCb, temp, rsp);
  rs_kernel<<<M_TOTAL / 256, 256, 0, stream>>>(rsp, rs);
  pass2_kernel<<<256 * KSPLIT, 512, 0, stream>>>(FZn, FCb, FCbT, temp, rs, probs, Up);
  zq_kernel<<<(M_TOTAL * DDIM / 4) / 256, 256, 0, stream>>>(Up, zq);
}